// Round 7
// baseline (1209.048 us; speedup 1.0000x reference)
//
#include <hip/hip_runtime.h>

#define LL 65536      // H*W
#define KSEL 655      // top-k count
#define EQCAP 8192

typedef unsigned short u16;
typedef __attribute__((ext_vector_type(8))) short s16x8;
typedef __attribute__((ext_vector_type(16))) float f32x16;

__device__ __forceinline__ u16 f2bf(float v) {
  unsigned u = __float_as_uint(v);
  u += 0x7FFFu + ((u >> 16) & 1u);
  return (u16)(u >> 16);
}
__device__ __forceinline__ float bf2f(u16 h) {
  return __uint_as_float(((unsigned)h) << 16);
}

// ---------------------------------------------------------------------------
// Zero the borders of a padded split-activation buffer:
// layout [16 planes (g=0..7 hi, 8..15 lo)][(H+2)][(W+2)][32ci].
// ---------------------------------------------------------------------------
__global__ void zb2_kernel(u16* __restrict__ buf, int H)
{
  const int H2 = H + 2;
  const int PS = H2*H2*32;
  const int per = (4*H2 - 4)*32;
  const int tot = 16*per;
  for (int t = blockIdx.x*blockDim.x + threadIdx.x; t < tot; t += gridDim.x*blockDim.x) {
    const int pl = t / per, e = t - pl*per;
    const int pix = e >> 5, cw = e & 31;
    int y, x;
    if (pix < H2)        { y = 0;      x = pix; }
    else if (pix < 2*H2) { y = H2-1;   x = pix - H2; }
    else { int k2 = pix - 2*H2; y = 1 + (k2 >> 1); x = (k2 & 1) ? (H2-1) : 0; }
    buf[(size_t)pl*PS + ((size_t)(y*H2 + x))*32 + cw] = 0;
  }
}

// ---------------------------------------------------------------------------
// Weight prep conv3x3 for 32x32x16 fragments.
// up_w (5, co256, ci256, 3,3) fp32 ->
// W3 flat: ((((((s*2+hl)*9+tap)*8+cob8)*8+ch)*2+kh))*512 + lane*8 + e
//   co = cob8*32 + (lane&31), ci = ch*32 + kh*16 + (lane>>5)*8 + e.
// grid: 5*8(ch)*8(cob8) = 320 blocks, 256 threads.
// ---------------------------------------------------------------------------
__global__ void __launch_bounds__(256) prep_w3_kernel(
    const float* __restrict__ up_w, u16* __restrict__ W3)
{
  const int b = blockIdx.x;
  const int cob8 = b & 7, ch = (b >> 3) & 7, s = b >> 6;
  const int tid = threadIdx.x;
  __shared__ float lds[32*292];   // [co_l][ci_l*9+tap], stride 292

  // load: per co_l, 288 contiguous floats (32 ci x 9 taps)
  for (int t = tid; t < 32*288; t += 256) {
    const int co_l = t / 288, r = t - co_l*288;
    lds[co_l*292 + r] = up_w[((size_t)((s*256 + cob8*32 + co_l)*256 + ch*32))*9 + r];
  }
  __syncthreads();

  // store: per (hl,tap,kh): 512 contiguous u16
  for (int u = tid; u < 18432; u += 256) {
    const int within = u & 511, c = u >> 9;
    const int kh = c & 1, tap = (c >> 1) % 9, hl = (c >> 1) / 9;
    const int lane_loc = within >> 3, e = within & 7;
    const int co_l = lane_loc & 31;
    const int ci_l = kh*16 + (lane_loc >> 5)*8 + e;
    const float v = lds[co_l*292 + ci_l*9 + tap];
    const u16 h = f2bf(v);
    const u16 val = hl ? f2bf(v - bf2f(h)) : h;
    const size_t addr = ((size_t)((((((s*2 + hl)*9 + tap)*8 + cob8)*8 + ch)*2 + kh)))*512 + within;
    W3[addr] = val;
  }
}

// ---------------------------------------------------------------------------
// Weight prep convT for 32x32x16 fragments.
// ct_w (5, ci256, co256, 4,4) fp32 ->
// W4 flat: ((((((s*2+hl)*16+pdt)*8+cob8)*8+ch)*2+kh))*512 + lane*8 + e
// pdt=p*4+dt; ky=3-py-2dy, kx=3-px-2dx.
// grid: 5*16(chh: ch,kh)*8(cob8) = 640 blocks.
// ---------------------------------------------------------------------------
__global__ void __launch_bounds__(256) prep_wt_kernel(
    const float* __restrict__ ct_w, u16* __restrict__ W4)
{
  const int b = blockIdx.x;
  const int cob8 = b & 7, chh = (b >> 3) & 15, s = b >> 7;
  const int ch = chh >> 1, kh = chh & 1;
  const int ci0 = ch*32 + kh*16;
  const int tid = threadIdx.x;
  __shared__ float lds[16*548];   // [ci_l][co_l*17 + tap], stride 548

  // load: per ci_l, 512 contiguous floats (32 co x 16 taps), pre-padded
  for (int t = tid; t < 16*512; t += 256) {
    const int ci_l = t >> 9, r = t & 511;
    lds[ci_l*548 + (r >> 4)*17 + (r & 15)] =
        ct_w[((size_t)((s*256 + ci0 + ci_l)*256 + cob8*32))*16 + r];
  }
  __syncthreads();

  // store: per (hl,pdt): 512 contiguous u16
  for (int u = tid; u < 16384; u += 256) {
    const int within = u & 511, c = u >> 9;
    const int pdt = c & 15, hl = c >> 4;
    const int lane_loc = within >> 3, e = within & 7;
    const int co_l = lane_loc & 31;
    const int ci_l = (lane_loc >> 5)*8 + e;
    const int p = pdt >> 2, dt = pdt & 3;
    const int py = p >> 1, px = p & 1, dy = dt >> 1, dx = dt & 1;
    const int ky = 3 - py - 2*dy, kx = 3 - px - 2*dx;
    const float v = lds[ci_l*548 + co_l*17 + ky*4 + kx];
    const u16 h = f2bf(v);
    const u16 val = hl ? f2bf(v - bf2f(h)) : h;
    const size_t addr = ((size_t)((((((s*2 + hl)*16 + pdt)*8 + cob8)*8 + ch)*2 + kh)))*512 + within;
    W4[addr] = val;
  }
}

// ---------------------------------------------------------------------------
// 1x1 conv: swinT (768,8,8) -> split activation buffer at res 8 (padded 10).
// ---------------------------------------------------------------------------
__global__ void __launch_bounds__(64) conv1x1_kernel(
    const float* __restrict__ swinT, const float* __restrict__ w,
    const float* __restrict__ b, u16* __restrict__ out)
{
  const int co = blockIdx.x, pp = threadIdx.x;
  float acc = b[co];
  for (int ci = 0; ci < 768; ++ci)
    acc += swinT[ci*64 + pp] * w[co*768 + ci];
  const int py = pp >> 3, px = pp & 7;
  const int g = co >> 5, cw = co & 31;
  const size_t o = (size_t)g*3200 + ((size_t)((py+1)*10 + px+1))*32 + cw;
  const u16 h = f2bf(acc);
  out[o] = h;
  out[o + (size_t)8*3200] = f2bf(acc - bf2f(h));
}

// ---------------------------------------------------------------------------
// conv3x3 via 32x32x16 MFMA (split bf16), no LDS. Weights = A operand
// (row=co), activations = B (col=x). Per wave: MI rows x 32 px x 32 co.
// grid (ceil(H/32), H/(4*MI), 8 co-blocks of 32), block 256.
// ---------------------------------------------------------------------------
template<int MI>
__global__ void __launch_bounds__(256, 2) conv3_mfma(
    const u16* __restrict__ in, const u16* __restrict__ W,
    const float* __restrict__ bias, u16* __restrict__ out, int H)
{
  const int H2 = H + 2;
  const int PS = H2*H2*32;
  const int tid = threadIdx.x;
  const int lane = tid & 63, wv = tid >> 6;
  const int lx32 = lane & 31, kq = lane >> 5;
  const int X0 = blockIdx.x*32, Y0 = blockIdx.y*(4*MI);
  const int cob8 = blockIdx.z;
  const int yl0 = wv*MI;

  f32x16 acc[MI] = {};
  const u16* Wl = W + lane*8;
  const int xoffB = (X0 + lx32)*32 + kq*8;

  for (int ch = 0; ch < 8; ++ch) {
    __builtin_amdgcn_s_barrier();   // phase-align waves for weight L1 reuse
    const u16* ph = in + (size_t)ch*PS;
    const u16* pl = ph + (size_t)8*PS;
    #pragma unroll
    for (int dxg = 0; dxg < 3; ++dxg) {
      s16x8 bh[MI+2][2], bl[MI+2][2];
      #pragma unroll
      for (int r = 0; r < MI+2; ++r)
        #pragma unroll
        for (int kh = 0; kh < 2; ++kh) {
          const size_t ro = (size_t)((Y0 + yl0 + r)*H2)*32 + xoffB + dxg*32 + kh*16;
          bh[r][kh] = *(const s16x8*)&ph[ro];
          bl[r][kh] = *(const s16x8*)&pl[ro];
        }
      #pragma unroll
      for (int dy = 0; dy < 3; ++dy) {
        const int tap = dy*3 + dxg;
        s16x8 ah[2], al[2];
        #pragma unroll
        for (int kh = 0; kh < 2; ++kh) {
          const int oh = (((tap*8 + cob8)*8 + ch)*2 + kh)*512;
          ah[kh] = *(const s16x8*)&Wl[oh];
          al[kh] = *(const s16x8*)&Wl[oh + 589824];   // hl stride = 9*8*8*2*512
        }
        #pragma unroll
        for (int mi = 0; mi < MI; ++mi)
          #pragma unroll
          for (int kh = 0; kh < 2; ++kh) {
            acc[mi] = __builtin_amdgcn_mfma_f32_32x32x16_bf16(ah[kh], bh[mi+dy][kh], acc[mi], 0, 0, 0);
            acc[mi] = __builtin_amdgcn_mfma_f32_32x32x16_bf16(al[kh], bh[mi+dy][kh], acc[mi], 0, 0, 0);
            acc[mi] = __builtin_amdgcn_mfma_f32_32x32x16_bf16(ah[kh], bl[mi+dy][kh], acc[mi], 0, 0, 0);
          }
      }
    }
  }

  // D: col(lane&31)=x, row = (reg&3) + 8*(reg>>2) + 4*kq = co within block.
  const int x = X0 + lx32;
  if (x < H) {
    #pragma unroll
    for (int rq = 0; rq < 4; ++rq) {
      const int cw = rq*8 + kq*4;
      const int co0 = cob8*32 + cw;
      const float4 bv = *(const float4*)&bias[co0];
      #pragma unroll
      for (int mi = 0; mi < MI; ++mi) {
        const int y = Y0 + yl0 + mi;
        const float v0 = acc[mi][rq*4+0] + bv.x;
        const float v1 = acc[mi][rq*4+1] + bv.y;
        const float v2 = acc[mi][rq*4+2] + bv.z;
        const float v3 = acc[mi][rq*4+3] + bv.w;
        const u16 h0 = f2bf(v0), h1 = f2bf(v1), h2 = f2bf(v2), h3 = f2bf(v3);
        const size_t o = (size_t)cob8*PS + ((size_t)((y+1)*H2 + x+1))*32 + cw;
        *(ushort4*)&out[o] = make_ushort4(h0, h1, h2, h3);
        *(ushort4*)&out[o + (size_t)8*PS] = make_ushort4(
            f2bf(v0 - bf2f(h0)), f2bf(v1 - bf2f(h1)),
            f2bf(v2 - bf2f(h2)), f2bf(v3 - bf2f(h3)));
      }
    }
  }
}

// ---------------------------------------------------------------------------
// ConvTranspose2d k4 s2 p1 + ReLU via 32x32x16 MFMA, parity-decomposed,
// no LDS. grid (ceil(Hin/32), Hin/(4*MI), 32: z = parity*8 + co-block).
// ---------------------------------------------------------------------------
template<int MI>
__global__ void __launch_bounds__(256, 2) convt_mfma(
    const u16* __restrict__ in, const u16* __restrict__ W,
    const float* __restrict__ bias, u16* __restrict__ out, int Hin)
{
  const int Hout = Hin*2;
  const int H2i = Hin + 2, H2o = Hout + 2;
  const int PSi = H2i*H2i*32, PSo = H2o*H2o*32;
  const int tid = threadIdx.x;
  const int lane = tid & 63, wv = tid >> 6;
  const int lx32 = lane & 31, kq = lane >> 5;
  const int X0 = blockIdx.x*32, Y0 = blockIdx.y*(4*MI);
  const int p = blockIdx.z >> 3, cob8 = blockIdx.z & 7;
  const int py = p >> 1, px = p & 1;
  const int yl0 = wv*MI;

  f32x16 acc[MI] = {};
  const u16* Wl = W + lane*8;
  const int xoffB = (X0 + px + lx32)*32 + kq*8;

  for (int ch = 0; ch < 8; ++ch) {
    __builtin_amdgcn_s_barrier();
    const u16* ph = in + (size_t)ch*PSi;
    const u16* pl = ph + (size_t)8*PSi;
    #pragma unroll
    for (int dx = 0; dx < 2; ++dx) {
      s16x8 bh[MI+1][2], bl[MI+1][2];
      #pragma unroll
      for (int r = 0; r < MI+1; ++r)
        #pragma unroll
        for (int kh = 0; kh < 2; ++kh) {
          const size_t ro = (size_t)((Y0 + yl0 + py + r)*H2i)*32 + xoffB + dx*32 + kh*16;
          bh[r][kh] = *(const s16x8*)&ph[ro];
          bl[r][kh] = *(const s16x8*)&pl[ro];
        }
      #pragma unroll
      for (int dy = 0; dy < 2; ++dy) {
        const int pdt = p*4 + dy*2 + dx;
        s16x8 ah[2], al[2];
        #pragma unroll
        for (int kh = 0; kh < 2; ++kh) {
          const int oh = (((pdt*8 + cob8)*8 + ch)*2 + kh)*512;
          ah[kh] = *(const s16x8*)&Wl[oh];
          al[kh] = *(const s16x8*)&Wl[oh + 1048576];  // hl stride = 16*8*8*2*512
        }
        #pragma unroll
        for (int mi = 0; mi < MI; ++mi)
          #pragma unroll
          for (int kh = 0; kh < 2; ++kh) {
            acc[mi] = __builtin_amdgcn_mfma_f32_32x32x16_bf16(ah[kh], bh[mi+dy][kh], acc[mi], 0, 0, 0);
            acc[mi] = __builtin_amdgcn_mfma_f32_32x32x16_bf16(al[kh], bh[mi+dy][kh], acc[mi], 0, 0, 0);
            acc[mi] = __builtin_amdgcn_mfma_f32_32x32x16_bf16(ah[kh], bl[mi+dy][kh], acc[mi], 0, 0, 0);
          }
      }
    }
  }

  const int xi = X0 + lx32;
  if (xi < Hin) {
    const int X = 2*xi + px;
    #pragma unroll
    for (int rq = 0; rq < 4; ++rq) {
      const int cw = rq*8 + kq*4;
      const int co0 = cob8*32 + cw;
      const float4 bv = *(const float4*)&bias[co0];
      #pragma unroll
      for (int mi = 0; mi < MI; ++mi) {
        const int Y = 2*(Y0 + yl0 + mi) + py;
        const float v0 = fmaxf(acc[mi][rq*4+0] + bv.x, 0.f);
        const float v1 = fmaxf(acc[mi][rq*4+1] + bv.y, 0.f);
        const float v2 = fmaxf(acc[mi][rq*4+2] + bv.z, 0.f);
        const float v3 = fmaxf(acc[mi][rq*4+3] + bv.w, 0.f);
        const u16 h0 = f2bf(v0), h1 = f2bf(v1), h2 = f2bf(v2), h3 = f2bf(v3);
        const size_t o = (size_t)cob8*PSo + ((size_t)((Y+1)*H2o + X+1))*32 + cw;
        *(ushort4*)&out[o] = make_ushort4(h0, h1, h2, h3);
        *(ushort4*)&out[o + (size_t)8*PSo] = make_ushort4(
            f2bf(v0 - bf2f(h0)), f2bf(v1 - bf2f(h1)),
            f2bf(v2 - bf2f(h2)), f2bf(v3 - bf2f(h3)));
      }
    }
  }
}

// ---------------------------------------------------------------------------
// gate[l] = sigmoid(sum_c down[c*L+l]*gw[c] + gb); block 0 zeroes top-k state.
// ---------------------------------------------------------------------------
__global__ void __launch_bounds__(256) gate_kernel(
    const float* __restrict__ down, const float* __restrict__ gw,
    const float* __restrict__ gb, float* __restrict__ gate,
    unsigned* __restrict__ hist, int* __restrict__ st, int* __restrict__ cnt)
{
  if (blockIdx.x == 0) {
    const int t = threadIdx.x;
    #pragma unroll
    for (int j = 0; j < 4; ++j) hist[j*256 + t] = 0;
    if (t == 0) { st[0] = 0; st[1] = KSEL; cnt[0] = 0; cnt[1] = 0; }
  }
  const int l = blockIdx.x*256 + threadIdx.x;
  float a0 = 0.f, a1 = 0.f, a2 = 0.f, a3 = 0.f;
  for (int c = 0; c < 256; c += 4) {
    a0 += down[(c+0)*LL + l] * gw[c+0];
    a1 += down[(c+1)*LL + l] * gw[c+1];
    a2 += down[(c+2)*LL + l] * gw[c+2];
    a3 += down[(c+3)*LL + l] * gw[c+3];
  }
  const float a = (a0+a1) + (a2+a3) + gb[0];
  gate[l] = 1.f / (1.f + expf(-a));
}

// ---------------------------------------------------------------------------
// Grid-wide exact top-K radix select (set semantics; ties -> lowest index).
// ---------------------------------------------------------------------------
__global__ void __launch_bounds__(256) tk_hist(
    const float* __restrict__ gate, const int* __restrict__ st,
    unsigned* __restrict__ hist, int pass)
{
  __shared__ unsigned lh[256];
  lh[threadIdx.x] = 0;
  __syncthreads();
  const unsigned pref = (unsigned)st[0];
  const int shift = 24 - 8*pass;
  for (int i = blockIdx.x*256 + threadIdx.x; i < LL; i += gridDim.x*256) {
    const unsigned u = __float_as_uint(gate[i]);
    const bool ok = (pass == 0) || ((u >> (shift + 8)) == pref);
    if (ok) atomicAdd(&lh[(u >> shift) & 255u], 1u);
  }
  __syncthreads();
  const unsigned c = lh[threadIdx.x];
  if (c) atomicAdd(&hist[pass*256 + threadIdx.x], c);
}

__global__ void tk_pick(const unsigned* __restrict__ hist, int* __restrict__ st, int pass)
{
  if (threadIdx.x != 0) return;
  const unsigned pref = (unsigned)st[0];
  int kk = st[1];
  const unsigned* h = hist + pass*256;
  int cum = 0, b = 255;
  for (; b >= 0; --b) {
    const int c = (int)h[b];
    if (cum + c >= kk) break;
    cum += c;
  }
  if (b < 0) b = 0;
  st[0] = (int)((pref << 8) | (unsigned)b);
  st[1] = kk - cum;
}

__global__ void __launch_bounds__(256) tk_compact(
    const float* __restrict__ gate, const int* __restrict__ st,
    int* __restrict__ sel, int* __restrict__ cnt, int* __restrict__ eqbuf)
{
  const unsigned T = (unsigned)st[0];
  for (int i = blockIdx.x*256 + threadIdx.x; i < LL; i += gridDim.x*256) {
    const unsigned u = __float_as_uint(gate[i]);
    if (u > T) {
      const int p = atomicAdd(&cnt[0], 1);
      sel[p] = i;
    } else if (u == T) {
      const int p = atomicAdd(&cnt[1], 1);
      if (p < EQCAP) eqbuf[p] = i;
    }
  }
}

__global__ void __launch_bounds__(1024) tk_fin(
    int* __restrict__ sel, const int* __restrict__ cnt, const int* __restrict__ eqbuf)
{
  const int g = cnt[0];
  const int need = KSEL - g;
  int M = cnt[1]; if (M > EQCAP) M = EQCAP;
  for (int x = threadIdx.x; x < M; x += 1024) {
    const int v = eqbuf[x];
    int rank = 0;
    for (int j = 0; j < M; ++j) rank += (eqbuf[j] < v);
    if (rank < need) sel[g + rank] = v;
  }
}

// ---------------------------------------------------------------------------
__global__ void __launch_bounds__(256) transpose_kernel(
    const float* __restrict__ in, float* __restrict__ out, int R, int Ck)
{
  __shared__ float t[32][33];
  const int bx = blockIdx.x*32, by = blockIdx.y*32;
  const int x = threadIdx.x & 31, y4 = threadIdx.x >> 5;
  #pragma unroll
  for (int i = 0; i < 4; ++i) {
    int r = by + y4 + i*8, c = bx + x;
    t[y4 + i*8][x] = (r < R && c < Ck) ? in[r*Ck + c] : 0.f;
  }
  __syncthreads();
  #pragma unroll
  for (int i = 0; i < 4; ++i) {
    int c = bx + y4 + i*8, r = by + x;
    if (c < Ck && r < R) out[c*R + r] = t[x][y4 + i*8];
  }
}

// ---------------------------------------------------------------------------
// Gather: q from down (C,L); kv from final split buffer (res 256, padded 258).
// ---------------------------------------------------------------------------
__global__ void __launch_bounds__(256) gather_kernel(
    const float* __restrict__ down, const u16* __restrict__ xf,
    const int* __restrict__ sel, float* __restrict__ q_in, float* __restrict__ kv_in)
{
  const int n = blockIdx.x, c = threadIdx.x;
  const int l = sel[n];
  q_in[n*256 + c] = down[c*LL + l];
  const int pr = (l >> 8) + 1, pc = (l & 255) + 1;
  const size_t PS = (size_t)258*258*32;
  const size_t o = (size_t)(c >> 5)*PS + ((size_t)(pr*258 + pc))*32 + (c & 31);
  kv_in[n*256 + c] = bf2f(xf[o]) + bf2f(xf[o + (size_t)8*PS]);
}

// ---------------------------------------------------------------------------
__global__ void __launch_bounds__(256) rowgemm_kernel(
    const float* __restrict__ WT, int wld,
    const float* __restrict__ srcA, const float* __restrict__ srcB,
    const float* __restrict__ bias, float* __restrict__ out, int N)
{
  const int g = blockIdx.y;
  const int tid = threadIdx.x;
  const int co = g*256 + tid;
  const float* src = (g == 0) ? srcA : srcB;
  float* outg = out + (size_t)g*(KSEL*256);
  __shared__ float Bl[16][256];
  const int n0 = blockIdx.x*16;
  #pragma unroll
  for (int j = 0; j < 16; ++j) {
    int n = n0 + j;
    Bl[j][tid] = (n < N) ? src[n*256 + tid] : 0.f;
  }
  __syncthreads();
  float acc[16];
  const float bv = bias[co];
  #pragma unroll
  for (int j = 0; j < 16; ++j) acc[j] = bv;
  #pragma unroll 4
  for (int ci = 0; ci < 256; ++ci) {
    const float w = WT[ci*wld + co];
    #pragma unroll
    for (int j = 0; j < 16; ++j) acc[j] += Bl[j][ci]*w;
  }
  #pragma unroll
  for (int j = 0; j < 16; ++j) {
    int n = n0 + j;
    if (n < N) outg[n*256 + tid] = acc[j];
  }
}

// ---------------------------------------------------------------------------
__global__ void __launch_bounds__(256) attn_kernel(
    const float* __restrict__ qb, const float* __restrict__ kb,
    const float* __restrict__ vb, float* __restrict__ ctx)
{
  const int n = blockIdx.x, h = blockIdx.y;
  const int tid = threadIdx.x;
  __shared__ float sc[KSEL];
  __shared__ float qv[32];
  __shared__ float red[4];
  __shared__ float part[8][32];
  __shared__ float s_mx, s_sum;

  if (tid < 32) qv[tid] = qb[n*256 + h*32 + tid];
  __syncthreads();

  const float scale = 0.17677669529663687f;
  for (int m = tid; m < KSEL; m += 256) {
    const float* kr = kb + m*256 + h*32;
    float s = 0.f;
    #pragma unroll
    for (int d = 0; d < 32; ++d) s += qv[d]*kr[d];
    sc[m] = s*scale;
  }
  __syncthreads();

  float lm = -1e30f;
  for (int m = tid; m < KSEL; m += 256) lm = fmaxf(lm, sc[m]);
  #pragma unroll
  for (int off = 32; off > 0; off >>= 1) lm = fmaxf(lm, __shfl_down(lm, off));
  if ((tid & 63) == 0) red[tid >> 6] = lm;
  __syncthreads();
  if (tid == 0) s_mx = fmaxf(fmaxf(red[0], red[1]), fmaxf(red[2], red[3]));
  __syncthreads();
  const float mx = s_mx;

  float ls = 0.f;
  for (int m = tid; m < KSEL; m += 256) {
    float pv = expf(sc[m] - mx);
    sc[m] = pv;
    ls += pv;
  }
  #pragma unroll
  for (int off = 32; off > 0; off >>= 1) ls += __shfl_down(ls, off);
  if ((tid & 63) == 0) red[tid >> 6] = ls;
  __syncthreads();
  if (tid == 0) s_sum = red[0]+red[1]+red[2]+red[3];
  __syncthreads();

  const int d = tid & 31, g = tid >> 5;
  float a = 0.f;
  for (int m = g; m < KSEL; m += 8) a += sc[m]*vb[m*256 + h*32 + d];
  part[g][d] = a;
  __syncthreads();
  if (tid < 32) {
    float s = 0.f;
    #pragma unroll
    for (int gg = 0; gg < 8; ++gg) s += part[gg][tid];
    ctx[n*256 + h*32 + tid] = s / s_sum;
  }
}

// ---------------------------------------------------------------------------
__global__ void __launch_bounds__(256) copy_kernel(
    const float4* __restrict__ src, float4* __restrict__ dst)
{
  const int i = blockIdx.x*256 + threadIdx.x;
  dst[i] = src[i];
}

__global__ void __launch_bounds__(256) scatter_kernel(
    const float* __restrict__ down, const float* __restrict__ gate,
    const int* __restrict__ sel, const float* __restrict__ att,
    float* __restrict__ out)
{
  const int n = blockIdx.x, c = threadIdx.x;
  const int l = sel[n];
  const float g = gate[l];
  const float dv = down[c*LL + l];
  out[c*LL + l] = g*att[n*256 + c] + (1.f - g)*dv;
}

// ---------------------------------------------------------------------------
extern "C" void kernel_launch(void* const* d_in, const int* in_sizes, int n_in,
                              void* d_out, int out_size, void* d_ws, size_t ws_size,
                              hipStream_t stream)
{
  (void)in_sizes; (void)n_in; (void)out_size; (void)ws_size;
  const float* down   = (const float*)d_in[0];
  const float* swinT  = (const float*)d_in[1];
  const float* wt_w   = (const float*)d_in[2];
  const float* wt_b   = (const float*)d_in[3];
  const float* ct_w   = (const float*)d_in[4];
  const float* ct_b   = (const float*)d_in[5];
  const float* up_w   = (const float*)d_in[6];
  const float* up_b   = (const float*)d_in[7];
  const float* gate_w = (const float*)d_in[8];
  const float* gate_b = (const float*)d_in[9];
  const float* ipw    = (const float*)d_in[10];
  const float* ipb    = (const float*)d_in[11];
  const float* ow     = (const float*)d_in[12];
  const float* ob     = (const float*)d_in[13];
  float* out = (float*)d_out;

  char* wsp = (char*)d_ws;
  size_t off = 0;
  auto take = [&](size_t bytes) -> void* {
    void* r = wsp + off;
    off += (bytes + 255) & ~(size_t)255;
    return r;
  };
  u16*      A     = (u16*)     take((size_t)16*258*258*32*sizeof(u16)); // 68.2 MB
  u16*      B     = (u16*)     take((size_t)16*258*258*32*sizeof(u16)); // 68.2 MB
  u16*      W3    = (u16*)     take((size_t)5898240*sizeof(u16));       // 11.8 MB
  u16*      W4    = (u16*)     take((size_t)10485760*sizeof(u16));      // 21.0 MB
  float*    gateb = (float*)   take((size_t)LL*sizeof(float));
  int*      sel   = (int*)     take(4096);
  unsigned* hist  = (unsigned*)take(4*256*sizeof(unsigned));
  int*      st    = (int*)     take(256);
  int*      cnt   = (int*)     take(256);
  int*      eqbuf = (int*)     take((size_t)EQCAP*sizeof(int));
  float*    WT    = (float*)   take((size_t)768*256*sizeof(float));
  float*    OWT   = (float*)   take((size_t)256*256*sizeof(float));
  float*    q_in  = (float*)   take((size_t)KSEL*256*sizeof(float));
  float*    kv_in = (float*)   take((size_t)KSEL*256*sizeof(float));
  float*    qkv   = (float*)   take((size_t)3*KSEL*256*sizeof(float));
  float*    ctx   = (float*)   take((size_t)KSEL*256*sizeof(float));
  float*    att   = (float*)   take((size_t)KSEL*256*sizeof(float));

  // ---- weight prep (LDS-tiled, coalesced, 32x32 fragment layout) ----
  prep_w3_kernel<<<320, 256, 0, stream>>>(up_w, W3);
  prep_wt_kernel<<<640, 256, 0, stream>>>(ct_w, W4);

  // ---- decoder pipeline ----
  auto zbBlocks = [](int H) { return (16*(4*(H+2) - 4)*32 + 255)/256; };
  zb2_kernel<<<zbBlocks(8), 256, 0, stream>>>(A, 8);
  conv1x1_kernel<<<256, 64, 0, stream>>>(swinT, wt_w, wt_b, A);
  int r = 8;
  for (int s = 0; s < 5; ++s) {
    const int o = 2*r;
    const u16* w4s = W4 + (size_t)s*2*16*65536;
    const u16* w3s = W3 + (size_t)s*2*9*65536;
    const float* cb = ct_b + s*256;
    const float* ub = up_b + s*256;

    zb2_kernel<<<zbBlocks(o), 256, 0, stream>>>(B, o);
    if (r >= 64)
      convt_mfma<4><<<dim3(r/32, r/16, 32), 256, 0, stream>>>(A, w4s, cb, B, r);
    else
      convt_mfma<1><<<dim3(1, r/4, 32), 256, 0, stream>>>(A, w4s, cb, B, r);

    zb2_kernel<<<zbBlocks(o), 256, 0, stream>>>(A, o);
    if (o >= 64)
      conv3_mfma<4><<<dim3(o/32, o/16, 8), 256, 0, stream>>>(B, w3s, ub, A, o);
    else
      conv3_mfma<1><<<dim3(1, o/4, 8), 256, 0, stream>>>(B, w3s, ub, A, o);
    r = o;
  }

  // ---- gate + top-k ----
  gate_kernel<<<256, 256, 0, stream>>>(down, gate_w, gate_b, gateb, hist, st, cnt);
  for (int p = 0; p < 4; ++p) {
    tk_hist<<<256, 256, 0, stream>>>(gateb, st, hist, p);
    tk_pick<<<1, 64, 0, stream>>>(hist, st, p);
  }
  tk_compact<<<256, 256, 0, stream>>>(gateb, st, sel, cnt, eqbuf);
  tk_fin<<<1, 1024, 0, stream>>>(sel, cnt, eqbuf);

  // ---- attention ----
  transpose_kernel<<<dim3(8, 24), 256, 0, stream>>>(ipw, WT, 768, 256);
  transpose_kernel<<<dim3(8, 8), 256, 0, stream>>>(ow, OWT, 256, 256);
  gather_kernel<<<KSEL, 256, 0, stream>>>(down, A, sel, q_in, kv_in);
  rowgemm_kernel<<<dim3(41, 3), 256, 0, stream>>>(WT, 768, q_in, kv_in, ipb, qkv, KSEL);
  attn_kernel<<<dim3(KSEL, 8), 256, 0, stream>>>(qkv, qkv + KSEL*256, qkv + 2*KSEL*256, ctx);
  rowgemm_kernel<<<dim3(41, 1), 256, 0, stream>>>(OWT, 256, ctx, ctx, ob, att, KSEL);

  // ---- output: copy down, then blend the selected pixels ----
  copy_kernel<<<16384, 256, 0, stream>>>((const float4*)down, (float4*)out);
  scatter_kernel<<<KSEL, 256, 0, stream>>>(down, gateb, sel, att, out);
}